// Round 5
// baseline (86.793 us; speedup 1.0000x reference)
//
#include <hip/hip_runtime.h>
#include <math.h>

// Problem constants: B=64, F=240, J=22, 16 segments, 5 paths.
#define BB 64
#define FF 240
#define NJ 22
#define NFRM (BB * FF)

// Segment joint tables bit-packed 5 bits/entry into constexpr immediates.
#define PK8(a0,a1,a2,a3,a4,a5,a6,a7) \
  (  (unsigned long long)(a0)        | ((unsigned long long)(a1) << 5)  \
   | ((unsigned long long)(a2) << 10)| ((unsigned long long)(a3) << 15) \
   | ((unsigned long long)(a4) << 20)| ((unsigned long long)(a5) << 25) \
   | ((unsigned long long)(a6) << 30)| ((unsigned long long)(a7) << 35) )
static constexpr unsigned long long SEG_S_LO = PK8(2,5,8,1,4,7,3,6);
static constexpr unsigned long long SEG_S_HI = PK8(9,12,14,17,19,13,16,18);
static constexpr unsigned long long SEG_E_LO = PK8(5,8,11,4,7,10,6,9);
static constexpr unsigned long long SEG_E_HI = PK8(12,15,17,19,21,16,18,20);
// Path offset/count tables, 5 bits/entry.
static constexpr unsigned PO_PK = 0u | (3u<<5) | (6u<<10) | (10u<<15) | (13u<<20);
static constexpr unsigned PC_PK = 3u | (3u<<5) | (4u<<10) | (3u<<15)  | (3u<<20);

struct F3 { float x, y, z; };
__device__ __forceinline__ F3 sub(F3 a, F3 b){ return {a.x-b.x, a.y-b.y, a.z-b.z}; }
__device__ __forceinline__ F3 crs(F3 a, F3 b){
    return {fmaf(a.y, b.z, -a.z*b.y), fmaf(a.z, b.x, -a.x*b.z), fmaf(a.x, b.y, -a.y*b.x)};
}
__device__ __forceinline__ float dt(F3 a, F3 b){ return fmaf(a.x, b.x, fmaf(a.y, b.y, a.z*b.z)); }
__device__ __forceinline__ float clamp1(float d){ return fminf(fmaxf(d, -1.0f), 1.0f); }

// Branchless asin, Abramowitz-Stegun 4.4.45 (3-term), |err| <= 6.8e-5 abs.
__device__ __forceinline__ float asin_fast(float d){
    float ax = fabsf(d);
    float p = fmaf(fmaf(fmaf(-0.0187293f, ax, 0.0742610f), ax, -0.2121144f), ax, 1.5707288f);
    float r = 1.57079632679f - sqrtf(1.0f - ax) * p;
    return copysignf(r, d);
}

// One block = ONE frame, one segment pair per thread (m = tid>>4, n = tid&15).
// Short per-wave runtime => barrier/tail overhead shrinks; 8 blocks/CU resident
// hide the staging latency. Two-stage 16x16 -> 5x5 reduction.
__global__ void __launch_bounds__(256) k_main(const float* __restrict__ m1,
                                              const float* __restrict__ m2,
                                              float* __restrict__ gp,
                                              int* __restrict__ flags){
    __shared__ __align__(8)  float pts[132];       // [0..65] motion1, [66..131] motion2
    __shared__ __align__(16) float seg[2][16][12]; // [motion][seg][sx sy sz ex ey ez pad..]
    __shared__ float g[256];                       // per-pair GLI, g[m*16+n]
    __shared__ float h[80];                        // stage-1: h[i*16+n] = sum over path i rows
    __shared__ float ext[2][4];                    // per-motion bbox: nx, xx, nz, xz
    int tid = threadIdx.x;
    int fr = blockIdx.x;

    // Stage: 33 float2 per motion (264 B each, consecutive).
    if (tid < 66){
        bool first = tid < 33;
        int u = first ? tid : tid - 33;
        const float2* src = first ? (const float2*)(m1 + (size_t)fr * 66)
                                  : (const float2*)(m2 + (size_t)fr * 66);
        ((float2*)pts)[(first ? 0 : 33) + u] = src[u];
    }
    __syncthreads();

    // Build segment-endpoint table (32 threads) + per-motion bbox (2 threads).
    if (tid < 32){
        int m = tid & 15, mot = tid >> 4;
        unsigned long long ps = (m < 8) ? SEG_S_LO : SEG_S_HI;
        unsigned long long pe = (m < 8) ? SEG_E_LO : SEG_E_HI;
        int sh = (m & 7) * 5;
        int js = (int)((ps >> sh) & 31);
        int je = (int)((pe >> sh) & 31);
        const float* P = pts + mot * 66;
        float* d = &seg[mot][m][0];
        d[0] = P[js*3]; d[1] = P[js*3+1]; d[2] = P[js*3+2];
        d[3] = P[je*3]; d[4] = P[je*3+1]; d[5] = P[je*3+2];
    } else if (tid < 34){
        int mot = tid - 32;
        const float* P = pts + mot * 66;
        float nx = 1e30f, xx = -1e30f, nz = 1e30f, xz = -1e30f;
        #pragma unroll
        for (int j = 0; j < NJ; ++j){
            float x = P[j*3], z = P[j*3+2];
            nx = fminf(nx, x); xx = fmaxf(xx, x);
            nz = fminf(nz, z); xz = fmaxf(xz, z);
        }
        ext[mot][0] = nx; ext[mot][1] = xx; ext[mot][2] = nz; ext[mot][3] = xz;
    }
    __syncthreads();

    // GLI: one pair per thread; 4 crosses / 4 rsqrts / 4 asins are independent.
    {
        int n = tid & 15, m = tid >> 4;
        float4 sa = *(const float4*)&seg[1][n][0];
        float2 sb = *(const float2*)&seg[1][n][4];
        F3 s2 = {sa.x, sa.y, sa.z};
        F3 e2 = {sa.w, sb.x, sb.y};
        float4 ta = *(const float4*)&seg[0][m][0];
        float2 tb = *(const float2*)&seg[0][m][4];
        F3 s1 = {ta.x, ta.y, ta.z};
        F3 e1 = {ta.w, tb.x, tb.y};

        F3 r13 = sub(s2, s1), r14 = sub(e2, s1);
        F3 r23 = sub(s2, e1), r24 = sub(e2, e1);
        F3 f0 = crs(r13, r14);
        F3 f1 = crs(r14, r24);
        F3 f2 = crs(r24, r23);
        F3 f3 = crs(r23, r13);
        float ss0 = dt(f0,f0), ss1 = dt(f1,f1), ss2 = dt(f2,f2), ss3 = dt(f3,f3);
        float i01 = rsqrtf(fmaxf(ss0*ss1, 1e-30f));
        float i12 = rsqrtf(fmaxf(ss1*ss2, 1e-30f));
        float i23 = rsqrtf(fmaxf(ss2*ss3, 1e-30f));
        float i30 = rsqrtf(fmaxf(ss3*ss0, 1e-30f));
        float t = asin_fast(clamp1(dt(f0,f1) * i01))
                + asin_fast(clamp1(dt(f1,f2) * i12))
                + asin_fast(clamp1(dt(f2,f3) * i23))
                + asin_fast(clamp1(dt(f3,f0) * i30));
        // (r34 x r12) . r13 == -(f3 . r14): ref negates when sign<=0, i.e. sg>=0.
        float sg = dt(f3, r14);
        g[tid] = (sg >= 0.0f ? -t : t) * 0.07957747154594767f;  // 1/(4*pi)
    }
    __syncthreads();

    // Stage-1 reduce (80 threads): h[i][n] = sum of g over path i's segments.
    if (tid < 80){
        int i = tid >> 4, n = tid & 15;
        int poi = (int)((PO_PK >> (i*5)) & 31), pci = (int)((PC_PK >> (i*5)) & 31);
        float s = 0.0f;
        for (int a = 0; a < pci; ++a) s += g[(poi + a) * 16 + n];
        h[i * 16 + n] = s;
    } else if (tid == 80){
        // bbox-overlap flag straight to global (ext ready since last barrier).
        flags[fr] = (ext[0][1] >= ext[1][0] && ext[1][1] >= ext[0][0] &&
                     ext[0][3] >= ext[1][2] && ext[1][3] >= ext[0][2]) ? 1 : 0;
    }
    __syncthreads();

    // Stage-2 reduce (25 threads): gp[b][pp][f], coalesced in f for k_vel.
    if (tid < 25){
        int i = tid / 5, j = tid - i * 5;
        int poj = (int)((PO_PK >> (j*5)) & 31), pcj = (int)((PC_PK >> (j*5)) & 31);
        float s = 0.0f;
        for (int b = 0; b < pcj; ++b) s += h[i * 16 + poj + b];
        int bb = fr / FF, f = fr - bb * FF;
        gp[((size_t)bb * 25 + tid) * FF + f] = s;
    }
}

// Masked frame-diff, max over 25 path-pairs. gp is [b][pp][f]: lane-contiguous in f.
__global__ void __launch_bounds__(256) k_vel(const float* __restrict__ gp,
                                             const int* __restrict__ flags,
                                             float* __restrict__ out){
    int b = blockIdx.x;
    int f = threadIdx.x;
    if (f >= FF - 1) return;
    const int* fl = flags + b * FF;

    int v0 = fl[f] | fl[f + 1];
    if (f > 0) v0 |= fl[f - 1];
    float mk0 = v0 ? 1.0f : 0.0f;

    int v1 = fl[f] | fl[f + 1];
    if (f + 2 < FF) v1 |= fl[f + 2];
    float mk1 = v1 ? 1.0f : 0.0f;

    const float* gb = gp + (size_t)b * 25 * FF + f;
    float mx = 0.0f;
    #pragma unroll
    for (int p = 0; p < 25; ++p){
        float g0 = gb[p * FF];
        float g1 = gb[p * FF + 1];
        float d = fabsf(g1 * mk1 - g0 * mk0);
        mx = fmaxf(mx, d);
    }
    out[b * (FF - 1) + f] = mx;
}

extern "C" void kernel_launch(void* const* d_in, const int* in_sizes, int n_in,
                              void* d_out, int out_size, void* d_ws, size_t ws_size,
                              hipStream_t stream) {
    const float* m1 = (const float*)d_in[0];
    const float* m2 = (const float*)d_in[1];
    float* gp    = (float*)d_ws;                                   // BB*25*FF floats
    int*   flags = (int*)((char*)d_ws + (size_t)BB * 25 * FF * 4); // NFRM ints
    float* out = (float*)d_out;

    k_main<<<NFRM, 256, 0, stream>>>(m1, m2, gp, flags);
    k_vel<<<BB, 256, 0, stream>>>(gp, flags, out);
}

// Round 6
// 83.111 us; speedup vs baseline: 1.0443x; 1.0443x over previous
//
#include <hip/hip_runtime.h>
#include <math.h>

// Problem constants: B=64, F=240, J=22, 16 segments, 5 paths.
#define BB 64
#define FF 240
#define NJ 22
#define NFRM (BB * FF)

// Segment joint tables bit-packed 5 bits/entry into constexpr immediates.
#define PK8(a0,a1,a2,a3,a4,a5,a6,a7) \
  (  (unsigned long long)(a0)        | ((unsigned long long)(a1) << 5)  \
   | ((unsigned long long)(a2) << 10)| ((unsigned long long)(a3) << 15) \
   | ((unsigned long long)(a4) << 20)| ((unsigned long long)(a5) << 25) \
   | ((unsigned long long)(a6) << 30)| ((unsigned long long)(a7) << 35) )
static constexpr unsigned long long SEG_S_LO = PK8(2,5,8,1,4,7,3,6);
static constexpr unsigned long long SEG_S_HI = PK8(9,12,14,17,19,13,16,18);
static constexpr unsigned long long SEG_E_LO = PK8(5,8,11,4,7,10,6,9);
static constexpr unsigned long long SEG_E_HI = PK8(12,15,17,19,21,16,18,20);
// Path offset/count tables, 5 bits/entry.
static constexpr unsigned PO_PK = 0u | (3u<<5) | (6u<<10) | (10u<<15) | (13u<<20);
static constexpr unsigned PC_PK = 3u | (3u<<5) | (4u<<10) | (3u<<15)  | (3u<<20);

struct F3 { float x, y, z; };
__device__ __forceinline__ F3 sub(F3 a, F3 b){ return {a.x-b.x, a.y-b.y, a.z-b.z}; }
__device__ __forceinline__ F3 crs(F3 a, F3 b){
    return {fmaf(a.y, b.z, -a.z*b.y), fmaf(a.z, b.x, -a.x*b.z), fmaf(a.x, b.y, -a.y*b.x)};
}
__device__ __forceinline__ float dt(F3 a, F3 b){ return fmaf(a.x, b.x, fmaf(a.y, b.y, a.z*b.z)); }
__device__ __forceinline__ float clamp1(float d){ return fminf(fmaxf(d, -1.0f), 1.0f); }

// Branchless asin, Abramowitz-Stegun 4.4.45 (3-term), |err| <= 6.8e-5 abs.
__device__ __forceinline__ float asin_fast(float d){
    float ax = fabsf(d);
    float p = fmaf(fmaf(fmaf(-0.0187293f, ax, 0.0742610f), ax, -0.2121144f), ax, 1.5707288f);
    float r = 1.57079632679f - sqrtf(1.0f - ax) * p;
    return copysignf(r, d);
}

// ONE WAVE per frame (64-thread workgroup): with a single-wave workgroup the
// compiler elides s_barrier (lockstep + lgkmcnt ordering), so all phase
// "__syncthreads" are free. Lane n=lane&15 fixes the motion2 segment; each
// lane computes 4 pairs (m = (lane>>4)+4k).
__global__ void __launch_bounds__(64, 4) k_main(const float* __restrict__ m1,
                                                const float* __restrict__ m2,
                                                float* __restrict__ gp,
                                                int* __restrict__ flags){
    __shared__ __align__(16) float pts[2][68];     // staged joints (66 used)
    __shared__ __align__(16) float seg[2][16][12]; // [motion][seg][sx sy sz ex ey ez pad..]
    __shared__ float g[256];                       // per-pair GLI, g[m*16+n]
    __shared__ float ext[8];                       // {nx,xx,nz,xz} x 2 motions
    int lane = threadIdx.x;
    int fr = blockIdx.x;

    // Stage 132 floats as float2 (base is 8B-aligned: fr*264 bytes).
    const float2* gsrc1 = (const float2*)(m1 + (size_t)fr * 66);
    const float2* gsrc2 = (const float2*)(m2 + (size_t)fr * 66);
    if (lane < 33) ((float2*)pts[0])[lane] = gsrc1[lane];
    if (lane >= 31){ int u = lane - 31; if (u < 33) ((float2*)pts[1])[u] = gsrc2[u]; }
    __syncthreads();

    // Lanes 0..31: segment-endpoint table. Lanes 32..39: bbox extrema (one per lane).
    if (lane < 32){
        int m = lane & 15, mot = lane >> 4;
        unsigned long long ps = (m < 8) ? SEG_S_LO : SEG_S_HI;
        unsigned long long pe = (m < 8) ? SEG_E_LO : SEG_E_HI;
        int sh = (m & 7) * 5;
        int js = (int)((ps >> sh) & 31);
        int je = (int)((pe >> sh) & 31);
        const float* P = pts[mot];
        float* d = &seg[mot][m][0];
        d[0] = P[js*3]; d[1] = P[js*3+1]; d[2] = P[js*3+2];
        d[3] = P[je*3]; d[4] = P[je*3+1]; d[5] = P[je*3+2];
    } else if (lane < 40){
        int sel = lane - 32;          // mot = sel>>2; within: 0=nx 1=xx 2=nz 3=xz
        int mot = sel >> 2;
        int c = sel & 2;              // 0 -> x, 2 -> z
        bool mx = sel & 1;            // max via -min(-v)
        const float* P = pts[mot];
        float a = 1e30f;
        #pragma unroll
        for (int j = 0; j < NJ; ++j){
            float v = P[j*3 + c];
            a = fminf(a, mx ? -v : v);
        }
        ext[sel] = mx ? -a : a;
    }
    __syncthreads();

    // GLI: 4 pairs per lane, phase-parallel.
    int n = lane & 15, q = lane >> 4;
    float4 sa = *(const float4*)&seg[1][n][0];
    float2 sb = *(const float2*)&seg[1][n][4];
    F3 s2 = {sa.x, sa.y, sa.z};
    F3 e2 = {sa.w, sb.x, sb.y};

    float rd01[4], rd12[4], rd23[4], rd30[4];
    float q01[4], q12[4], q23[4], q30[4];
    float sg[4];
    #pragma unroll
    for (int k = 0; k < 4; ++k){
        int m = q + 4 * k;
        float4 ta = *(const float4*)&seg[0][m][0];
        float2 tb = *(const float2*)&seg[0][m][4];
        F3 s1 = {ta.x, ta.y, ta.z};
        F3 e1 = {ta.w, tb.x, tb.y};
        F3 r13 = sub(s2, s1), r14 = sub(e2, s1);
        F3 r23 = sub(s2, e1), r24 = sub(e2, e1);
        F3 f0 = crs(r13, r14);
        F3 f1 = crs(r14, r24);
        F3 f2 = crs(r24, r23);
        F3 f3 = crs(r23, r13);
        float ss0 = dt(f0,f0), ss1 = dt(f1,f1), ss2 = dt(f2,f2), ss3 = dt(f3,f3);
        rd01[k] = dt(f0,f1); rd12[k] = dt(f1,f2);
        rd23[k] = dt(f2,f3); rd30[k] = dt(f3,f0);
        q01[k] = ss0*ss1; q12[k] = ss1*ss2; q23[k] = ss2*ss3; q30[k] = ss3*ss0;
        // (r34 x r12) . r13 == -(f3 . r14): reuse f3, skip the 5th cross.
        sg[k] = dt(f3, r14);
    }
    float i01[4], i12[4], i23[4], i30[4];
    #pragma unroll
    for (int k = 0; k < 4; ++k){
        i01[k] = rsqrtf(fmaxf(q01[k], 1e-30f));
        i12[k] = rsqrtf(fmaxf(q12[k], 1e-30f));
        i23[k] = rsqrtf(fmaxf(q23[k], 1e-30f));
        i30[k] = rsqrtf(fmaxf(q30[k], 1e-30f));
    }
    #pragma unroll
    for (int k = 0; k < 4; ++k){
        float t = asin_fast(clamp1(rd01[k] * i01[k]))
                + asin_fast(clamp1(rd12[k] * i12[k]))
                + asin_fast(clamp1(rd23[k] * i23[k]))
                + asin_fast(clamp1(rd30[k] * i30[k]));
        // ref: mult = (sign<=0) ? -1 : 1, sign = -sg  =>  negate when sg >= 0.
        float r = (sg[k] >= 0.0f ? -t : t) * 0.07957747154594767f;  // 1/(4*pi)
        g[(q + 4*k) * 16 + n] = r;
    }
    __syncthreads();

    // Lanes 0..24: direct path-pair sums -> gp[b][pp][f]. Lane 25: overlap flag.
    if (lane < 25){
        int i = lane / 5, j = lane - i * 5;
        int poi = (int)((PO_PK >> (i*5)) & 31), pci = (int)((PC_PK >> (i*5)) & 31);
        int poj = (int)((PO_PK >> (j*5)) & 31), pcj = (int)((PC_PK >> (j*5)) & 31);
        float s = 0.0f;
        for (int a = 0; a < pci; ++a)
            for (int b = 0; b < pcj; ++b)
                s += g[(poi + a) * 16 + (poj + b)];
        int bb = fr / FF, f = fr - bb * FF;
        gp[((size_t)bb * 25 + lane) * FF + f] = s;
    } else if (lane == 25){
        flags[fr] = (ext[1] >= ext[4] && ext[5] >= ext[0] &&
                     ext[3] >= ext[6] && ext[7] >= ext[2]) ? 1 : 0;
    }
}

// Masked frame-diff, max over 25 path-pairs. gp is [b][pp][f]: lane-contiguous in f.
__global__ void __launch_bounds__(256) k_vel(const float* __restrict__ gp,
                                             const int* __restrict__ flags,
                                             float* __restrict__ out){
    int b = blockIdx.x;
    int f = threadIdx.x;
    if (f >= FF - 1) return;
    const int* fl = flags + b * FF;

    int v0 = fl[f] | fl[f + 1];
    if (f > 0) v0 |= fl[f - 1];
    float mk0 = v0 ? 1.0f : 0.0f;

    int v1 = fl[f] | fl[f + 1];
    if (f + 2 < FF) v1 |= fl[f + 2];
    float mk1 = v1 ? 1.0f : 0.0f;

    const float* gb = gp + (size_t)b * 25 * FF + f;
    float mx = 0.0f;
    #pragma unroll
    for (int p = 0; p < 25; ++p){
        float g0 = gb[p * FF];
        float g1 = gb[p * FF + 1];
        float d = fabsf(g1 * mk1 - g0 * mk0);
        mx = fmaxf(mx, d);
    }
    out[b * (FF - 1) + f] = mx;
}

extern "C" void kernel_launch(void* const* d_in, const int* in_sizes, int n_in,
                              void* d_out, int out_size, void* d_ws, size_t ws_size,
                              hipStream_t stream) {
    const float* m1 = (const float*)d_in[0];
    const float* m2 = (const float*)d_in[1];
    float* gp    = (float*)d_ws;                                   // BB*25*FF floats
    int*   flags = (int*)((char*)d_ws + (size_t)BB * 25 * FF * 4); // NFRM ints
    float* out = (float*)d_out;

    k_main<<<NFRM, 64, 0, stream>>>(m1, m2, gp, flags);
    k_vel<<<BB, 256, 0, stream>>>(gp, flags, out);
}

// Round 8
// 81.762 us; speedup vs baseline: 1.0615x; 1.0165x over previous
//
#include <hip/hip_runtime.h>
#include <math.h>

// Problem constants: B=64, F=240, J=22, 16 segments, 5 paths.
#define BB 64
#define FF 240
#define NJ 22
#define NFRM (BB * FF)

// Segment joint tables bit-packed 5 bits/entry into constexpr immediates.
#define PK8(a0,a1,a2,a3,a4,a5,a6,a7) \
  (  (unsigned long long)(a0)        | ((unsigned long long)(a1) << 5)  \
   | ((unsigned long long)(a2) << 10)| ((unsigned long long)(a3) << 15) \
   | ((unsigned long long)(a4) << 20)| ((unsigned long long)(a5) << 25) \
   | ((unsigned long long)(a6) << 30)| ((unsigned long long)(a7) << 35) )
static constexpr unsigned long long SEG_S_LO = PK8(2,5,8,1,4,7,3,6);
static constexpr unsigned long long SEG_S_HI = PK8(9,12,14,17,19,13,16,18);
static constexpr unsigned long long SEG_E_LO = PK8(5,8,11,4,7,10,6,9);
static constexpr unsigned long long SEG_E_HI = PK8(12,15,17,19,21,16,18,20);
// Path offset/count tables, 5 bits/entry.
static constexpr unsigned PO_PK = 0u | (3u<<5) | (6u<<10) | (10u<<15) | (13u<<20);
static constexpr unsigned PC_PK = 3u | (3u<<5) | (4u<<10) | (3u<<15)  | (3u<<20);

struct F3 { float x, y, z; };
__device__ __forceinline__ F3 sub(F3 a, F3 b){ return {a.x-b.x, a.y-b.y, a.z-b.z}; }
__device__ __forceinline__ F3 crs(F3 a, F3 b){
    return {fmaf(a.y, b.z, -a.z*b.y), fmaf(a.z, b.x, -a.x*b.z), fmaf(a.x, b.y, -a.y*b.x)};
}
__device__ __forceinline__ float dt(F3 a, F3 b){ return fmaf(a.x, b.x, fmaf(a.y, b.y, a.z*b.z)); }
__device__ __forceinline__ float clamp1(float d){ return fminf(fmaxf(d, -1.0f), 1.0f); }

// Branchless asin, Abramowitz-Stegun 4.4.45 (3-term), |err| <= 6.8e-5 abs.
// __builtin_amdgcn_sqrtf = raw v_sqrt_f32 (arg in [0,2], no denormal fixup needed).
__device__ __forceinline__ float asin_fast(float d){
    float ax = fabsf(d);
    float p = fmaf(fmaf(fmaf(-0.0187293f, ax, 0.0742610f), ax, -0.2121144f), ax, 1.5707288f);
    float r = 1.57079632679f - __builtin_amdgcn_sqrtf(1.0f - ax) * p;
    return copysignf(r, d);
}

// 128-thread workgroup = 2 waves, one FRAME per wave. Per-CU workgroup-slot cap
// (~16 WGs/CU) limited 64-thread blocks to 16 waves/CU; 2-wave blocks restore
// 32 waves/CU while keeping barriers cheap (2 symmetric waves).
// Per wave: lane n=lane&15 fixes the motion2 segment; each lane computes 4
// pairs (m = (lane>>4)+4k), then lanes 0..24 reduce to the 5x5 path blocks.
__global__ void __launch_bounds__(128, 8) k_main(const float* __restrict__ m1,
                                                 const float* __restrict__ m2,
                                                 float* __restrict__ gp,
                                                 int* __restrict__ flags){
    __shared__ __align__(16) float pts[2][2][68];     // [wave][motion][joint floats]
    __shared__ __align__(16) float seg[2][2][16][12]; // [wave][motion][seg][sx sy sz ex ey ez pad]
    __shared__ float g[2][256];                       // [wave][m*16+n]
    __shared__ float ext[2][8];                       // [wave][{nx,xx,nz,xz} x 2 motions]
    int tid = threadIdx.x;
    int w = tid >> 6, lane = tid & 63;
    int fr = blockIdx.x * 2 + w;

    // Stage 132 floats per frame as float2 (base 8B-aligned: fr*264 bytes).
    const float2* gsrc1 = (const float2*)(m1 + (size_t)fr * 66);
    const float2* gsrc2 = (const float2*)(m2 + (size_t)fr * 66);
    if (lane < 33) ((float2*)pts[w][0])[lane] = gsrc1[lane];
    if (lane >= 31){ int u = lane - 31; if (u < 33) ((float2*)pts[w][1])[u] = gsrc2[u]; }
    __syncthreads();

    // Lanes 0..31: segment-endpoint table. Lanes 32..39: bbox extrema (one per lane).
    if (lane < 32){
        int m = lane & 15, mot = lane >> 4;
        unsigned long long ps = (m < 8) ? SEG_S_LO : SEG_S_HI;
        unsigned long long pe = (m < 8) ? SEG_E_LO : SEG_E_HI;
        int sh = (m & 7) * 5;
        int js = (int)((ps >> sh) & 31);
        int je = (int)((pe >> sh) & 31);
        const float* P = pts[w][mot];
        float* d = &seg[w][mot][m][0];
        d[0] = P[js*3]; d[1] = P[js*3+1]; d[2] = P[js*3+2];
        d[3] = P[je*3]; d[4] = P[je*3+1]; d[5] = P[je*3+2];
    } else if (lane < 40){
        int sel = lane - 32;          // mot = sel>>2; within: 0=nx 1=xx 2=nz 3=xz
        int mot = sel >> 2;
        int c = sel & 2;              // 0 -> x, 2 -> z
        bool mx = sel & 1;            // max via -min(-v)
        const float* P = pts[w][mot];
        float a = 1e30f;
        #pragma unroll
        for (int j = 0; j < NJ; ++j){
            float v = P[j*3 + c];
            a = fminf(a, mx ? -v : v);
        }
        ext[w][sel] = mx ? -a : a;
    }
    __syncthreads();

    // GLI: 4 pairs per lane, phase-parallel.
    int n = lane & 15, q = lane >> 4;
    float4 sa = *(const float4*)&seg[w][1][n][0];
    float2 sb = *(const float2*)&seg[w][1][n][4];
    F3 s2 = {sa.x, sa.y, sa.z};
    F3 e2 = {sa.w, sb.x, sb.y};

    float rd01[4], rd12[4], rd23[4], rd30[4];
    float q01[4], q12[4], q23[4], q30[4];
    float sg[4];
    #pragma unroll
    for (int k = 0; k < 4; ++k){
        int m = q + 4 * k;
        float4 ta = *(const float4*)&seg[w][0][m][0];
        float2 tb = *(const float2*)&seg[w][0][m][4];
        F3 s1 = {ta.x, ta.y, ta.z};
        F3 e1 = {ta.w, tb.x, tb.y};
        F3 r13 = sub(s2, s1), r14 = sub(e2, s1);
        F3 r23 = sub(s2, e1), r24 = sub(e2, e1);
        F3 f0 = crs(r13, r14);
        F3 f1 = crs(r14, r24);
        F3 f2 = crs(r24, r23);
        F3 f3 = crs(r23, r13);
        float ss0 = dt(f0,f0), ss1 = dt(f1,f1), ss2 = dt(f2,f2), ss3 = dt(f3,f3);
        rd01[k] = dt(f0,f1); rd12[k] = dt(f1,f2);
        rd23[k] = dt(f2,f3); rd30[k] = dt(f3,f0);
        q01[k] = ss0*ss1; q12[k] = ss1*ss2; q23[k] = ss2*ss3; q30[k] = ss3*ss0;
        // (r34 x r12) . r13 == -(f3 . r14): reuse f3, skip the 5th cross.
        sg[k] = dt(f3, r14);
    }
    float i01[4], i12[4], i23[4], i30[4];
    #pragma unroll
    for (int k = 0; k < 4; ++k){
        i01[k] = rsqrtf(fmaxf(q01[k], 1e-30f));
        i12[k] = rsqrtf(fmaxf(q12[k], 1e-30f));
        i23[k] = rsqrtf(fmaxf(q23[k], 1e-30f));
        i30[k] = rsqrtf(fmaxf(q30[k], 1e-30f));
    }
    #pragma unroll
    for (int k = 0; k < 4; ++k){
        float t = asin_fast(clamp1(rd01[k] * i01[k]))
                + asin_fast(clamp1(rd12[k] * i12[k]))
                + asin_fast(clamp1(rd23[k] * i23[k]))
                + asin_fast(clamp1(rd30[k] * i30[k]));
        // ref: mult = (sign<=0) ? -1 : 1, sign = -sg  =>  negate when sg >= 0.
        float r = (sg[k] >= 0.0f ? -t : t) * 0.07957747154594767f;  // 1/(4*pi)
        g[w][(k << 6) | lane] = r;   // (q+4k)*16+n == 64k + lane: contiguous
    }
    __syncthreads();

    // Lanes 0..24: direct path-pair sums -> gp[b][pp][f]. Lane 25: overlap flag.
    if (lane < 25){
        int i = lane / 5, j = lane - i * 5;
        int poi = (int)((PO_PK >> (i*5)) & 31), pci = (int)((PC_PK >> (i*5)) & 31);
        int poj = (int)((PO_PK >> (j*5)) & 31), pcj = (int)((PC_PK >> (j*5)) & 31);
        float s = 0.0f;
        for (int a = 0; a < pci; ++a)
            for (int b = 0; b < pcj; ++b)
                s += g[w][(poi + a) * 16 + (poj + b)];
        int bb = fr / FF, f = fr - bb * FF;
        gp[((size_t)bb * 25 + lane) * FF + f] = s;
    } else if (lane == 25){
        flags[fr] = (ext[w][1] >= ext[w][4] && ext[w][5] >= ext[w][0] &&
                     ext[w][3] >= ext[w][6] && ext[w][7] >= ext[w][2]) ? 1 : 0;
    }
}

// Masked frame-diff, max over 25 path-pairs. gp is [b][pp][f]: lane-contiguous in f.
__global__ void __launch_bounds__(256) k_vel(const float* __restrict__ gp,
                                             const int* __restrict__ flags,
                                             float* __restrict__ out){
    int b = blockIdx.x;
    int f = threadIdx.x;
    if (f >= FF - 1) return;
    const int* fl = flags + b * FF;

    int v0 = fl[f] | fl[f + 1];
    if (f > 0) v0 |= fl[f - 1];
    float mk0 = v0 ? 1.0f : 0.0f;

    int v1 = fl[f] | fl[f + 1];
    if (f + 2 < FF) v1 |= fl[f + 2];
    float mk1 = v1 ? 1.0f : 0.0f;

    const float* gb = gp + (size_t)b * 25 * FF + f;
    float mx = 0.0f;
    #pragma unroll
    for (int p = 0; p < 25; ++p){
        float g0 = gb[p * FF];
        float g1 = gb[p * FF + 1];
        float d = fabsf(g1 * mk1 - g0 * mk0);
        mx = fmaxf(mx, d);
    }
    out[b * (FF - 1) + f] = mx;
}

extern "C" void kernel_launch(void* const* d_in, const int* in_sizes, int n_in,
                              void* d_out, int out_size, void* d_ws, size_t ws_size,
                              hipStream_t stream) {
    const float* m1 = (const float*)d_in[0];
    const float* m2 = (const float*)d_in[1];
    float* gp    = (float*)d_ws;                                   // BB*25*FF floats
    int*   flags = (int*)((char*)d_ws + (size_t)BB * 25 * FF * 4); // NFRM ints
    float* out = (float*)d_out;

    k_main<<<NFRM / 2, 128, 0, stream>>>(m1, m2, gp, flags);
    k_vel<<<BB, 256, 0, stream>>>(gp, flags, out);
}

// Round 9
// 78.219 us; speedup vs baseline: 1.1096x; 1.0453x over previous
//
#include <hip/hip_runtime.h>
#include <math.h>

// Problem constants: B=64, F=240, J=22, 16 segments, 5 paths.
#define BB 64
#define FF 240
#define NJ 22
#define NFRM (BB * FF)

// Segment joint tables bit-packed 5 bits/entry into constexpr immediates.
#define PK8(a0,a1,a2,a3,a4,a5,a6,a7) \
  (  (unsigned long long)(a0)        | ((unsigned long long)(a1) << 5)  \
   | ((unsigned long long)(a2) << 10)| ((unsigned long long)(a3) << 15) \
   | ((unsigned long long)(a4) << 20)| ((unsigned long long)(a5) << 25) \
   | ((unsigned long long)(a6) << 30)| ((unsigned long long)(a7) << 35) )
static constexpr unsigned long long SEG_S_LO = PK8(2,5,8,1,4,7,3,6);
static constexpr unsigned long long SEG_S_HI = PK8(9,12,14,17,19,13,16,18);
static constexpr unsigned long long SEG_E_LO = PK8(5,8,11,4,7,10,6,9);
static constexpr unsigned long long SEG_E_HI = PK8(12,15,17,19,21,16,18,20);
// Path offset/count tables, 5 bits/entry.
static constexpr unsigned PO_PK = 0u | (3u<<5) | (6u<<10) | (10u<<15) | (13u<<20);
static constexpr unsigned PC_PK = 3u | (3u<<5) | (4u<<10) | (3u<<15)  | (3u<<20);

struct F3 { float x, y, z; };
__device__ __forceinline__ F3 sub(F3 a, F3 b){ return {a.x-b.x, a.y-b.y, a.z-b.z}; }
__device__ __forceinline__ F3 crs(F3 a, F3 b){
    return {fmaf(a.y, b.z, -a.z*b.y), fmaf(a.z, b.x, -a.x*b.z), fmaf(a.x, b.y, -a.y*b.x)};
}
__device__ __forceinline__ float dt(F3 a, F3 b){ return fmaf(a.x, b.x, fmaf(a.y, b.y, a.z*b.z)); }
__device__ __forceinline__ float clamp1(float d){ return fminf(fmaxf(d, -1.0f), 1.0f); }

// Branchless asin, Abramowitz-Stegun 4.4.45 (3-term), |err| <= 6.8e-5 abs.
__device__ __forceinline__ float asin_fast(float d){
    float ax = fabsf(d);
    float p = fmaf(fmaf(fmaf(-0.0187293f, ax, 0.0742610f), ax, -0.2121144f), ax, 1.5707288f);
    float r = 1.57079632679f - __builtin_amdgcn_sqrtf(1.0f - ax) * p;
    return copysignf(r, d);
}

// 256-thread block = 4 waves; each wave owns TWO frames (block = 8 frames).
// Each lane runs 8 independent GLI pair-chains (2 frames x 4 pairs),
// phase-parallel, with __launch_bounds__(256,4) (<=128 VGPR) so the register
// allocator cannot re-serialize them into one long chain. Seg-build uses all
// 64 lanes (2 frames x 32 entries); reduction uses 52/64 lanes.
__global__ void __launch_bounds__(256, 4) k_main(const float* __restrict__ m1,
                                                 const float* __restrict__ m2,
                                                 float* __restrict__ gp,
                                                 int* __restrict__ flags){
    __shared__ __align__(16) float pts[4][2][136];    // [wave][motion][frame*66+...], 132 used
    __shared__ __align__(8)  float seg[4][2][2][16][6];// [wave][frame][motion][seg][6]
    __shared__ float g[4][2][256];                    // [wave][frame][m*16+n]
    __shared__ float ext[4][2][8];                    // [wave][frame][{nx,xx,nz,xz} x 2 motions]
    int tid = threadIdx.x;
    int w = tid >> 6, lane = tid & 63;
    int fr0 = blockIdx.x * 8 + w * 2;   // this wave's frames: fr0, fr0+1

    // Stage 2 frames x 66 floats from each motion = 66 float2 per motion,
    // contiguous in global (frames adjacent). 132 float2 over 64 lanes.
    const float2* gs1 = (const float2*)(m1 + (size_t)fr0 * 66);
    const float2* gs2 = (const float2*)(m2 + (size_t)fr0 * 66);
    for (int u = lane; u < 132; u += 64){
        bool a = u < 66;
        int v = a ? u : u - 66;
        ((float2*)pts[w][a ? 0 : 1])[v] = (a ? gs1 : gs2)[v];
    }
    __syncthreads();

    // Segment-endpoint table: all 64 lanes busy (2 frames x 2 motions x 16 segs).
    {
        int m = lane & 15, mot = (lane >> 4) & 1, f = lane >> 5;
        unsigned long long ps = (m < 8) ? SEG_S_LO : SEG_S_HI;
        unsigned long long pe = (m < 8) ? SEG_E_LO : SEG_E_HI;
        int sh = (m & 7) * 5;
        int js = (int)((ps >> sh) & 31);
        int je = (int)((pe >> sh) & 31);
        const float* P = &pts[w][mot][f * 66];
        float* d = &seg[w][f][mot][m][0];
        d[0] = P[js*3]; d[1] = P[js*3+1]; d[2] = P[js*3+2];
        d[3] = P[je*3]; d[4] = P[je*3+1]; d[5] = P[je*3+2];
    }
    // Bbox extrema: 16 lanes, one extremum each (2 frames x 2 motions x {x,z} x {min,max}).
    if (lane < 16){
        int f = lane >> 3, mot = (lane >> 2) & 1;
        int c = lane & 2;            // 0 -> x, 2 -> z
        bool mx = lane & 1;          // max via -min(-v)
        const float* P = &pts[w][mot][f * 66];
        float a = 1e30f;
        #pragma unroll
        for (int j = 0; j < NJ; ++j){
            float v = P[j*3 + c];
            a = fminf(a, mx ? -v : v);
        }
        ext[w][f][lane & 7] = mx ? -a : a;
    }
    __syncthreads();

    // GLI: 8 independent pair-chains per lane (f in {0,1}, k in {0..3}).
    int n = lane & 15, q = lane >> 4;
    F3 s2f[2], e2f[2];
    #pragma unroll
    for (int f = 0; f < 2; ++f){
        const float* B = &seg[w][f][1][n][0];
        float2 b0 = *(const float2*)(B+0);
        float2 b1 = *(const float2*)(B+2);
        float2 b2 = *(const float2*)(B+4);
        s2f[f] = {b0.x, b0.y, b1.x};
        e2f[f] = {b1.y, b2.x, b2.y};
    }

    float rd01[2][4], rd12[2][4], rd23[2][4], rd30[2][4];
    float q01[2][4], q12[2][4], q23[2][4], q30[2][4];
    float sg[2][4];
    #pragma unroll
    for (int f = 0; f < 2; ++f){
        F3 s2 = s2f[f], e2 = e2f[f];
        #pragma unroll
        for (int k = 0; k < 4; ++k){
            int m = q + 4 * k;
            const float* A = &seg[w][f][0][m][0];
            float2 a0 = *(const float2*)(A+0);
            float2 a1 = *(const float2*)(A+2);
            float2 a2 = *(const float2*)(A+4);
            F3 s1 = {a0.x, a0.y, a1.x};
            F3 e1 = {a1.y, a2.x, a2.y};
            F3 r13 = sub(s2, s1), r14 = sub(e2, s1);
            F3 r23 = sub(s2, e1), r24 = sub(e2, e1);
            F3 f0 = crs(r13, r14);
            F3 f1 = crs(r14, r24);
            F3 f2 = crs(r24, r23);
            F3 f3 = crs(r23, r13);
            float ss0 = dt(f0,f0), ss1 = dt(f1,f1), ss2 = dt(f2,f2), ss3 = dt(f3,f3);
            rd01[f][k] = dt(f0,f1); rd12[f][k] = dt(f1,f2);
            rd23[f][k] = dt(f2,f3); rd30[f][k] = dt(f3,f0);
            q01[f][k] = ss0*ss1; q12[f][k] = ss1*ss2;
            q23[f][k] = ss2*ss3; q30[f][k] = ss3*ss0;
            // (r34 x r12) . r13 == -(f3 . r14): reuse f3, skip the 5th cross.
            sg[f][k] = dt(f3, r14);
        }
    }
    // 32 independent rsqrts.
    float i01[2][4], i12[2][4], i23[2][4], i30[2][4];
    #pragma unroll
    for (int f = 0; f < 2; ++f)
    #pragma unroll
    for (int k = 0; k < 4; ++k){
        i01[f][k] = rsqrtf(fmaxf(q01[f][k], 1e-30f));
        i12[f][k] = rsqrtf(fmaxf(q12[f][k], 1e-30f));
        i23[f][k] = rsqrtf(fmaxf(q23[f][k], 1e-30f));
        i30[f][k] = rsqrtf(fmaxf(q30[f][k], 1e-30f));
    }
    // 32 asin groups + combine + store.
    #pragma unroll
    for (int f = 0; f < 2; ++f)
    #pragma unroll
    for (int k = 0; k < 4; ++k){
        float t = asin_fast(clamp1(rd01[f][k] * i01[f][k]))
                + asin_fast(clamp1(rd12[f][k] * i12[f][k]))
                + asin_fast(clamp1(rd23[f][k] * i23[f][k]))
                + asin_fast(clamp1(rd30[f][k] * i30[f][k]));
        // ref: mult = (sign<=0) ? -1 : 1, sign = -sg  =>  negate when sg >= 0.
        float r = (sg[f][k] >= 0.0f ? -t : t) * 0.07957747154594767f;  // 1/(4*pi)
        g[w][f][(k << 6) | lane] = r;   // (q+4k)*16+n == 64k+lane
    }
    __syncthreads();

    // Lanes 0..49: path-pair sums for both frames -> gp[b][pp][f] (coalesced for
    // k_vel). Lanes 50..51: the two overlap flags.
    if (lane < 50){
        int f = lane >= 25 ? 1 : 0;
        int pp = lane - f * 25;
        int i = pp / 5, j = pp - i * 5;
        int poi = (int)((PO_PK >> (i*5)) & 31), pci = (int)((PC_PK >> (i*5)) & 31);
        int poj = (int)((PO_PK >> (j*5)) & 31), pcj = (int)((PC_PK >> (j*5)) & 31);
        float s = 0.0f;
        for (int a = 0; a < pci; ++a)
            for (int b = 0; b < pcj; ++b)
                s += g[w][f][(poi + a) * 16 + (poj + b)];
        int fr = fr0 + f;
        int bb = fr / FF, ff = fr - bb * FF;
        gp[((size_t)bb * 25 + pp) * FF + ff] = s;
    } else if (lane < 52){
        int f = lane - 50;
        const float* e = ext[w][f];
        flags[fr0 + f] = (e[1] >= e[4] && e[5] >= e[0] &&
                          e[3] >= e[6] && e[7] >= e[2]) ? 1 : 0;
    }
}

// Masked frame-diff, max over 25 path-pairs. gp is [b][pp][f]: lane-contiguous in f.
__global__ void __launch_bounds__(256) k_vel(const float* __restrict__ gp,
                                             const int* __restrict__ flags,
                                             float* __restrict__ out){
    int b = blockIdx.x;
    int f = threadIdx.x;
    if (f >= FF - 1) return;
    const int* fl = flags + b * FF;

    int v0 = fl[f] | fl[f + 1];
    if (f > 0) v0 |= fl[f - 1];
    float mk0 = v0 ? 1.0f : 0.0f;

    int v1 = fl[f] | fl[f + 1];
    if (f + 2 < FF) v1 |= fl[f + 2];
    float mk1 = v1 ? 1.0f : 0.0f;

    const float* gb = gp + (size_t)b * 25 * FF + f;
    float mx = 0.0f;
    #pragma unroll
    for (int p = 0; p < 25; ++p){
        float g0 = gb[p * FF];
        float g1 = gb[p * FF + 1];
        float d = fabsf(g1 * mk1 - g0 * mk0);
        mx = fmaxf(mx, d);
    }
    out[b * (FF - 1) + f] = mx;
}

extern "C" void kernel_launch(void* const* d_in, const int* in_sizes, int n_in,
                              void* d_out, int out_size, void* d_ws, size_t ws_size,
                              hipStream_t stream) {
    const float* m1 = (const float*)d_in[0];
    const float* m2 = (const float*)d_in[1];
    float* gp    = (float*)d_ws;                                   // BB*25*FF floats
    int*   flags = (int*)((char*)d_ws + (size_t)BB * 25 * FF * 4); // NFRM ints
    float* out = (float*)d_out;

    k_main<<<NFRM / 8, 256, 0, stream>>>(m1, m2, gp, flags);
    k_vel<<<BB, 256, 0, stream>>>(gp, flags, out);
}